// Round 2
// baseline (124.085 us; speedup 1.0000x reference)
//
#include <hip/hip_runtime.h>

namespace {

constexpr int T = 512;
constexpr int K = 4;
constexpr int G = 20000;
constexpr int EPG = 3;
constexpr int B = 512;
constexpr int GPAD = 20480;       // 20 g-blocks x 1024
constexpr int ROWSTRIDE = 36;     // dwords per t-row in LDS (144 B) -> conflict-free
constexpr size_t H2_BYTES = (size_t)B * T * K * 4;  // 4 MB
constexpr float SLOPE = 0.01f;

__device__ __forceinline__ float lrelu(float x) { return x > 0.0f ? x : SLOPE * x; }

// Kernel 1: h2[b][t][k] (unchanged from R1 - fast)
__global__ __launch_bounds__(256) void h2_kernel(
    const float* __restrict__ features, const float* __restrict__ w1,
    const float* __restrict__ b1, const float* __restrict__ w2,
    const float* __restrict__ b2, float* __restrict__ h2out) {
  const int t = blockIdx.x * 256 + threadIdx.x;
  const int b = blockIdx.y;
  const float f = features[b * T + t];
  const float4 W1 = reinterpret_cast<const float4*>(w1)[t];
  const float4 B1 = reinterpret_cast<const float4*>(b1)[t];
  const float4 B2 = reinterpret_cast<const float4*>(b2)[t];
  const float h0 = lrelu(f * W1.x + B1.x);
  const float h1 = lrelu(f * W1.y + B1.y);
  const float h2 = lrelu(f * W1.z + B1.z);
  const float h3 = lrelu(f * W1.w + B1.w);
  const float4* W2 = reinterpret_cast<const float4*>(w2 + (size_t)t * (K * K));
  const float4 r0 = W2[0];
  const float4 r1 = W2[1];
  const float4 r2 = W2[2];
  const float4 r3 = W2[3];
  float4 o;
  o.x = lrelu(B2.x + h0 * r0.x + h1 * r1.x + h2 * r2.x + h3 * r3.x);
  o.y = lrelu(B2.y + h0 * r0.y + h1 * r1.y + h2 * r2.y + h3 * r3.y);
  o.z = lrelu(B2.z + h0 * r0.z + h1 * r1.z + h2 * r2.z + h3 * r3.z);
  o.w = lrelu(B2.w + h0 * r0.w + h1 * r1.w + h2 * r2.w + h3 * r3.w);
  reinterpret_cast<float4*>(h2out)[b * T + t] = o;
}

// Prep: pack per-g record = [w3_e0(4f), w3_e1(4f), w3_e2(4f), bias, ldsoff0, ldsoff1, ldsoff2]
__global__ __launch_bounds__(256) void prep_kernel(
    const float* __restrict__ w3, const float* __restrict__ b3,
    const int* __restrict__ edge, float4* __restrict__ rec) {
  const int g = blockIdx.x * 256 + threadIdx.x;  // 0..GPAD-1
  float4 a = make_float4(0.f, 0.f, 0.f, 0.f), b = a, c = a, d = a;
  if (g < G) {
    const float4* wp = reinterpret_cast<const float4*>(w3 + (size_t)g * (EPG * K));
    a = wp[0];
    b = wp[1];
    c = wp[2];
    d.x = b3[g];
    d.y = __int_as_float(ROWSTRIDE * 4 * edge[g * EPG + 0]);  // byte offset 144*t
    d.z = __int_as_float(ROWSTRIDE * 4 * edge[g * EPG + 1]);
    d.w = __int_as_float(ROWSTRIDE * 4 * edge[g * EPG + 2]);
  } else {
    d.y = d.z = d.w = __int_as_float(0);
  }
  float4* o = rec + (size_t)g * 4;
  o[0] = a; o[1] = b; o[2] = c; o[3] = d;
}

// Kernel 2 v2: LDS layout lds[t][b(8)][k] with 36-dword row stride.
// lane = (gsub = tid>>3, bidx = tid&7): 8-lane clusters with the SAME g read a
// contiguous, 32-bank-covering 128 B chunk -> ds_read_b128 at its 8-phase
// minimum for ANY t. Staging writes are uniform 8-way (also the minimum).
__global__ __launch_bounds__(256) void out_kernel_v2(
    const float* __restrict__ h2, const float4* __restrict__ rec,
    float* __restrict__ out) {
  extern __shared__ float lds[];  // 512 * 36 dwords = 73728 B
  const int tid = threadIdx.x;
  const int gbase = blockIdx.x * 1024;
  const int b0 = blockIdx.y * 8;

  // stage 8 b-rows (64 KB): coalesced global b128 reads, optimal LDS b128 writes
  {
    const float4* src = reinterpret_cast<const float4*>(h2 + (size_t)b0 * (T * K));
#pragma unroll
    for (int j = 0; j < 16; ++j) {
      const int f = j * 256 + tid;      // 0..4095
      const int bb = f >> 9;            // 0..7
      const int t = f & 511;
      const float4 v = src[(size_t)bb * T + t];
      *reinterpret_cast<float4*>(lds + ROWSTRIDE * t + 4 * bb) = v;
    }
  }
  __syncthreads();

  const int bidx = tid & 7;
  const int gsub = tid >> 3;  // 0..31
  const char* ldsb = reinterpret_cast<const char*>(lds);
  const int laneoff = bidx * 16;

  // software-pipelined g-loop: prefetch next record while computing current
  float4 p0, p1, p2, p3;
  {
    const float4* r = rec + (size_t)(gbase + gsub) * 4;
    p0 = r[0]; p1 = r[1]; p2 = r[2]; p3 = r[3];
  }
#pragma unroll 4
  for (int s = 0; s < 32; ++s) {
    const float4 c0 = p0, c1 = p1, c2 = p2, c3 = p3;
    const int g = gbase + s * 32 + gsub;
    if (s + 1 < 32) {
      const float4* r = rec + (size_t)(gbase + (s + 1) * 32 + gsub) * 4;
      p0 = r[0]; p1 = r[1]; p2 = r[2]; p3 = r[3];
    }
    const float4 v0 = *reinterpret_cast<const float4*>(ldsb + (__float_as_int(c3.y) + laneoff));
    const float4 v1 = *reinterpret_cast<const float4*>(ldsb + (__float_as_int(c3.z) + laneoff));
    const float4 v2 = *reinterpret_cast<const float4*>(ldsb + (__float_as_int(c3.w) + laneoff));
    float acc = c3.x;
    acc += v0.x * c0.x + v0.y * c0.y + v0.z * c0.z + v0.w * c0.w;
    acc += v1.x * c1.x + v1.y * c1.y + v1.z * c1.z + v1.w * c1.w;
    acc += v2.x * c2.x + v2.y * c2.y + v2.z * c2.z + v2.w * c2.w;
    if (g < G) out[(size_t)(b0 + bidx) * G + g] = acc;
  }
}

}  // namespace

extern "C" void kernel_launch(void* const* d_in, const int* in_sizes, int n_in,
                              void* d_out, int out_size, void* d_ws, size_t ws_size,
                              hipStream_t stream) {
  const float* features = (const float*)d_in[0];
  const float* w1 = (const float*)d_in[1];
  const float* b1 = (const float*)d_in[2];
  const float* w2 = (const float*)d_in[3];
  const float* b2 = (const float*)d_in[4];
  const float* w3 = (const float*)d_in[5];
  const float* b3 = (const float*)d_in[6];
  const int* edge = (const int*)d_in[7];
  float* out = (float*)d_out;

  float* h2buf = (float*)d_ws;                                  // 4 MB
  float4* rec = (float4*)((char*)d_ws + H2_BYTES);              // 20480 * 64 B

  dim3 g1(T / 256, B);
  h2_kernel<<<g1, 256, 0, stream>>>(features, w1, b1, w2, b2, h2buf);

  prep_kernel<<<GPAD / 256, 256, 0, stream>>>(w3, b3, edge, rec);

  static bool attr_set = false;  // harmless host-side attribute (idempotent)
  if (!attr_set) {
    hipFuncSetAttribute((const void*)out_kernel_v2,
                        hipFuncAttributeMaxDynamicSharedMemorySize,
                        T * ROWSTRIDE * 4);
    attr_set = true;
  }
  dim3 g2(GPAD / 1024, B / 8);  // (20, 64)
  out_kernel_v2<<<g2, 256, T * ROWSTRIDE * 4, stream>>>(h2buf, rec, out);
}

// Round 3
// 107.580 us; speedup vs baseline: 1.1534x; 1.1534x over previous
//
#include <hip/hip_runtime.h>

namespace {

constexpr int T = 512;
constexpr int K = 4;
constexpr int G = 20000;
constexpr int EPG = 3;
constexpr int B = 512;
constexpr int GC = 16;        // g's per out-block
constexpr int NGB = G / GC;   // 1250 (exact)
constexpr int LPAD = 20;      // LDS row stride (dwords), 16B-aligned, conflict-free
constexpr float SLOPE = 0.01f;
constexpr size_t H2T_OFF = 2u << 20;  // rec at ws+0 (1.28 MB), h2T at ws+2MB (4 MB)

__device__ __forceinline__ float lrelu(float x) { return x > 0.0f ? x : SLOPE * x; }

// Kernel 1: h2T[t][b][k] = lrelu(...) -- transposed layout so the out-kernel's
// gather (uniform t, lane=b) is a perfectly coalesced float4 load.
// t = blockIdx.x (params become wave-uniform scalar loads), b = lane.
__global__ __launch_bounds__(256) void h2t_kernel(
    const float* __restrict__ features, const float* __restrict__ w1,
    const float* __restrict__ b1, const float* __restrict__ w2,
    const float* __restrict__ b2, float* __restrict__ h2t) {
  const int t = blockIdx.x;
  const int b = blockIdx.y * 256 + threadIdx.x;
  const float f = features[(size_t)b * T + t];  // strided 4B reads; 1MB array, L2-hot
  const float4 W1 = reinterpret_cast<const float4*>(w1)[t];
  const float4 B1 = reinterpret_cast<const float4*>(b1)[t];
  const float4 B2 = reinterpret_cast<const float4*>(b2)[t];
  const float h0 = lrelu(f * W1.x + B1.x);
  const float h1 = lrelu(f * W1.y + B1.y);
  const float h2 = lrelu(f * W1.z + B1.z);
  const float h3 = lrelu(f * W1.w + B1.w);
  const float4* W2 = reinterpret_cast<const float4*>(w2 + (size_t)t * (K * K));
  const float4 r0 = W2[0];
  const float4 r1 = W2[1];
  const float4 r2 = W2[2];
  const float4 r3 = W2[3];
  float4 o;
  o.x = lrelu(B2.x + h0 * r0.x + h1 * r1.x + h2 * r2.x + h3 * r3.x);
  o.y = lrelu(B2.y + h0 * r0.y + h1 * r1.y + h2 * r2.y + h3 * r3.y);
  o.z = lrelu(B2.z + h0 * r0.z + h1 * r1.z + h2 * r2.z + h3 * r3.z);
  o.w = lrelu(B2.w + h0 * r0.w + h1 * r1.w + h2 * r2.w + h3 * r3.w);
  reinterpret_cast<float4*>(h2t)[(size_t)t * B + b] = o;  // coalesced 16B/lane
}

// Prep: per-g 64B record = [w3_e0, w3_e1, w3_e2, (bias, byteoff0, byteoff1, byteoff2)]
// byteoff_e = t_e * B*K*4 (row offset into h2T).
__global__ __launch_bounds__(256) void prep_kernel(
    const float* __restrict__ w3, const float* __restrict__ b3,
    const int* __restrict__ edge, float4* __restrict__ rec) {
  const int g = blockIdx.x * 256 + threadIdx.x;
  if (g >= G) return;
  const float4* wp = reinterpret_cast<const float4*>(w3 + (size_t)g * (EPG * K));
  const float4 a = wp[0], b = wp[1], c = wp[2];
  float4 d;
  d.x = b3[g];
  d.y = __int_as_float(edge[g * EPG + 0] * (B * K * 4));
  d.z = __int_as_float(edge[g * EPG + 1] * (B * K * 4));
  d.w = __int_as_float(edge[g * EPG + 2] * (B * K * 4));
  float4* o = rec + (size_t)g * 4;
  o[0] = a; o[1] = b; o[2] = c; o[3] = d;
}

// Kernel 2 v3: block = 256 b's (lane=b), GC=16 uniform g's per block.
// rec loads are block-uniform (scalar); h2T loads are coalesced b128; acc in
// registers; 20KB LDS transpose makes the out stores coalesced.
__global__ __launch_bounds__(256) void out_kernel_v3(
    const float* __restrict__ h2t, const float4* __restrict__ rec,
    float* __restrict__ out) {
  __shared__ float lds[256 * LPAD];
  const int tid = threadIdx.x;
  const int g0 = blockIdx.x * GC;
  const char* h2b = reinterpret_cast<const char*>(h2t) +
                    ((size_t)blockIdx.y * 256 + tid) * 16;
  float acc[GC];
#pragma unroll
  for (int gi = 0; gi < GC; ++gi) {
    const float4* r = rec + (size_t)(g0 + gi) * 4;  // uniform -> s_load
    const float4 w0 = r[0];
    const float4 w1v = r[1];
    const float4 w2v = r[2];
    const float4 m = r[3];
    const float4 v0 = *reinterpret_cast<const float4*>(h2b + __float_as_int(m.y));
    const float4 v1 = *reinterpret_cast<const float4*>(h2b + __float_as_int(m.z));
    const float4 v2 = *reinterpret_cast<const float4*>(h2b + __float_as_int(m.w));
    float a = m.x;
    a += v0.x * w0.x + v0.y * w0.y + v0.z * w0.z + v0.w * w0.w;
    a += v1.x * w1v.x + v1.y * w1v.y + v1.z * w1v.z + v1.w * w1v.w;
    a += v2.x * w2v.x + v2.y * w2v.y + v2.z * w2v.z + v2.w * w2v.w;
    acc[gi] = a;
  }
  // registers -> LDS (b128 writes, stride 20 dwords: conflict-free 8-phase)
#pragma unroll
  for (int q = 0; q < GC / 4; ++q)
    *reinterpret_cast<float4*>(&lds[tid * LPAD + q * 4]) =
        make_float4(acc[q * 4 + 0], acc[q * 4 + 1], acc[q * 4 + 2], acc[q * 4 + 3]);
  __syncthreads();
  // LDS -> out: per wave-instr 4 b-rows x 16 g = 4x64B segments (coalesced)
#pragma unroll
  for (int j = 0; j < GC; ++j) {
    const int flat = j * 256 + tid;
    const int brow = flat >> 4;
    const int gcol = flat & 15;
    out[((size_t)blockIdx.y * 256 + brow) * G + g0 + gcol] = lds[brow * LPAD + gcol];
  }
}

}  // namespace

extern "C" void kernel_launch(void* const* d_in, const int* in_sizes, int n_in,
                              void* d_out, int out_size, void* d_ws, size_t ws_size,
                              hipStream_t stream) {
  const float* features = (const float*)d_in[0];
  const float* w1 = (const float*)d_in[1];
  const float* b1 = (const float*)d_in[2];
  const float* w2 = (const float*)d_in[3];
  const float* b2 = (const float*)d_in[4];
  const float* w3 = (const float*)d_in[5];
  const float* b3 = (const float*)d_in[6];
  const int* edge = (const int*)d_in[7];
  float* out = (float*)d_out;

  float4* rec = (float4*)d_ws;                          // 20000*64 B = 1.28 MB
  float* h2t = (float*)((char*)d_ws + H2T_OFF);         // 4 MB

  dim3 g1(T, B / 256);  // (512, 2)
  h2t_kernel<<<g1, 256, 0, stream>>>(features, w1, b1, w2, b2, h2t);

  prep_kernel<<<(G + 255) / 256, 256, 0, stream>>>(w3, b3, edge, rec);

  dim3 g2(NGB, B / 256);  // (1250, 2); x-fast dispatch keeps one b-slab per L2
  out_kernel_v3<<<g2, 256, 0, stream>>>(h2t, rec, out);
}